// Round 14
// baseline (208.740 us; speedup 1.0000x reference)
//
#include <hip/hip_runtime.h>
#include <hip/hip_bf16.h>

// B=4, L=S=1024, D=1024, H=16, HD=64. History: R16 256^2/BK=64 8-wave GEMMs
// (proj 192 blk, o-proj 128 blk). R19: attn QBLK=128 swapped QK^T + T2-
// involution P + b64 P-store + Q-in-regs -> 210.2. R20 regrid ✗, R21 TLP ✗,
// R22 T15 ✗ (lesson x4: work-per-barrier dominates). R23: + T5 setprio on
// attn MFMA clusters -> 207.1 (best; attn < 41us, top-5 all harness fills).
// R24: attn KVBLK 64->128 — halves syncthreads/block (16->8), doubles GLD
// batch per drain; per-64-s half keeps ALL verified machinery (Past layout,
// involution, b64 store, wave_barrier, setprio). K frag=(h*4+j)*2+kk,
// V frag=j*4+h*2+kk. LDS 48->80KB dynamic; occupancy stays 2 blk/CU
// (grid-limited). If neutral: R23 is the plateau.

typedef __bf16 bf16;
typedef __bf16 bf16x4 __attribute__((ext_vector_type(4)));
typedef __bf16 bf16x8 __attribute__((ext_vector_type(8)));
typedef float floatx4 __attribute__((ext_vector_type(4)));

#define D_MODEL 1024
#define NHEAD   16
#define HDIM    64
#define BATCH   4
#define SEQ     1024
#define M_ROWS  (BATCH * SEQ)         // 4096
#define ACT_N   ((size_t)M_ROWS * D_MODEL)    // 4M
#define W_N     ((size_t)D_MODEL * D_MODEL)   // 1M
#define SC2     0.18033688011112042f  // 0.125 * log2(e)

#define GLD(gp, lp) __builtin_amdgcn_global_load_lds( \
    (__attribute__((address_space(1))) void*)(gp), \
    (__attribute__((address_space(3))) void*)(lp), 16, 0, 0)

// ---------------------------------------------------------------------------
// Fused convert + mask (R10-verbatim, verified).
// ---------------------------------------------------------------------------
__global__ __launch_bounds__(256)
void k_convert_all(const float* __restrict__ a0, const float* __restrict__ a1,
                   const float* __restrict__ a2,
                   const float* __restrict__ w0, const float* __restrict__ w1,
                   const float* __restrict__ w2, const float* __restrict__ w3,
                   bf16* __restrict__ dst,
                   const unsigned* __restrict__ m, float* __restrict__ mbias)
{
    if (blockIdx.x == 8192) {
        __shared__ unsigned viol[4];
        __shared__ int fmsh;
        if (threadIdx.x < 4) viol[threadIdx.x] = 0;
        __syncthreads();
        unsigned a = 0, b = 0, c = 0, d = 0;
        for (int i = threadIdx.x; i < 1024; i += 256) {
            unsigned v = m[i];
            if (v > 1u) a = 1;
            if (((v & 0xFFu) > 1u) || (((v >> 8) & 0xFFu) > 1u) ||
                (((v >> 16) & 0xFFu) > 1u) || (((v >> 24) & 0xFFu) > 1u)) b = 1;
            unsigned lo = v & 0xFFFFu, hi = v >> 16;
            if (!((lo == 0u || lo == 0x3F80u) && (hi == 0u || hi == 0x3F80u))) c = 1;
            if (lo != 0u) d = 1;
        }
        if (a) atomicOr(&viol[0], 1u);
        if (b) atomicOr(&viol[1], 1u);
        if (c) atomicOr(&viol[2], 1u);
        if (d) atomicOr(&viol[3], 1u);
        __syncthreads();
        if (threadIdx.x == 0) {
            int fm;
            if (!viol[0])      fm = 1;
            else if (!viol[1]) fm = 0;
            else if (!viol[2]) fm = viol[3] ? 2 : 3;
            else               fm = 0;
            fmsh = fm;
        }
        __syncthreads();
        const int fm = fmsh;
        for (int i = 0; i < 16; ++i) {
            int s = i * 256 + threadIdx.x;
            bool msk;
            if (fm == 1)      msk = ((const int*)m)[s] != 0;
            else if (fm == 2) msk = ((const unsigned short*)m)[s] != 0;
            else if (fm == 3) msk = ((const unsigned*)m)[s] != 0;
            else              msk = ((const unsigned char*)m)[s] != 0;
            mbias[s] = msk ? -1e30f : 0.f;
        }
        return;
    }

    size_t i = ((size_t)blockIdx.x * 256 + threadIdx.x) * 8;
    const float* src; size_t off;
    if (i < ((size_t)12 << 20)) {
        int z = (int)(i >> 22);
        src = (z == 0) ? a0 : (z == 1) ? a1 : a2;
        off = i & (((size_t)1 << 22) - 1);
    } else {
        size_t r = i - ((size_t)12 << 20);
        int j = (int)(r >> 20);
        src = (j == 0) ? w0 : (j == 1) ? w1 : (j == 2) ? w2 : w3;
        off = r & (((size_t)1 << 20) - 1);
    }
    float4 f0 = ((const float4*)(src + off))[0];
    float4 f1 = ((const float4*)(src + off))[1];
    bf16x8 o;
    o[0] = (bf16)f0.x; o[1] = (bf16)f0.y; o[2] = (bf16)f0.z; o[3] = (bf16)f0.w;
    o[4] = (bf16)f1.x; o[5] = (bf16)f1.y; o[6] = (bf16)f1.z; o[7] = (bf16)f1.w;
    *(bf16x8*)(dst + i) = o;
}

// ---------------------------------------------------------------------------
// 256xNT / BK=64 / 8-wave GEMM core (R16-verified at NT=256, R17 at NT=128).
// ---------------------------------------------------------------------------
template<typename CT, int NT>
__device__ __forceinline__ void gemm8_core(const bf16* __restrict__ A,
                                           const bf16* __restrict__ W,
                                           const float* __restrict__ bias,
                                           CT* __restrict__ C,
                                           int m0, int n0, bool rowBias,
                                           bf16* __restrict__ As0,
                                           bf16* __restrict__ Bs0)
{
    const int t    = threadIdx.x;     // 0..511
    const int lane = t & 63;
    const int w    = t >> 6;          // 0..7
    const int wm   = w >> 2;          // 0..1
    const int wn   = w & 3;           // 0..3
    const int l15  = lane & 15;
    const int quad = lane >> 4;
    const int lx   = l15 & 7;

    constexpr int NJ = NT / 128;      // B jj-count per quadrant (2 or 1)
    constexpr int BSTRIDE = NT * 64;  // elems per B buffer

    floatx4 acc[8][NT / 64] = {};

    int srow[2], schk[2], ldso[2];
    #pragma unroll
    for (int j = 0; j < 2; ++j) {
        int i = j * 512 + t;
        srow[j] = i >> 3;
        schk[j] = (i & 7) ^ (srow[j] & 7);
        ldso[j] = (j * 512 + w * 64) * 8;
    }

    #define STAGE_HALF(src, rb, k0s, h, dstbuf) do {                          \
        _Pragma("unroll")                                                     \
        for (int j = 0; j < 2; ++j)                                           \
            GLD((src) + (size_t)((rb) + (h) * 128 + srow[j]) * D_MODEL        \
                    + (k0s) + schk[j] * 8,                                    \
                (dstbuf) + (h) * 8192 + ldso[j]);                             \
    } while (0)

    // prologue: tile 0 -> buffer 0
    STAGE_HALF(A, m0, 0, 0, As0);
    STAGE_HALF(A, m0, 0, 1, As0);
    STAGE_HALF(W, n0, 0, 0, Bs0);
    if constexpr (NT == 256) STAGE_HALF(W, n0, 0, 1, Bs0);
    __syncthreads();

    for (int kt = 0; kt < 16; ++kt) {
        const int nk = (kt + 1) * 64;
        const bf16* __restrict__ Ab = As0 + (kt & 1) * 16384;
        const bf16* __restrict__ Bb = Bs0 + (kt & 1) * BSTRIDE;
        bf16* __restrict__ An = As0 + ((kt + 1) & 1) * 16384;
        bf16* __restrict__ Bn = Bs0 + ((kt + 1) & 1) * BSTRIDE;

        #pragma unroll
        for (int ph = 0; ph < 4; ++ph) {
            const int mq = ph >> 1, nq = ph & 1;

            if (nk < D_MODEL) {       // stage one half of tile kt+1
                if constexpr (NT == 256) {
                    if (ph == 0)      STAGE_HALF(A, m0, nk, 0, An);
                    else if (ph == 1) STAGE_HALF(A, m0, nk, 1, An);
                    else if (ph == 2) STAGE_HALF(W, n0, nk, 0, Bn);
                    else              STAGE_HALF(W, n0, nk, 1, Bn);
                } else {
                    if (ph == 0)      STAGE_HALF(A, m0, nk, 0, An);
                    else if (ph == 1) STAGE_HALF(A, m0, nk, 1, An);
                    else if (ph == 2) STAGE_HALF(W, n0, nk, 0, Bn);
                }
            }

            bf16x8 af[4][2], bfr[NJ][2];
            #pragma unroll
            for (int ii = 0; ii < 4; ++ii) {
                int row = wm * 128 + mq * 64 + ii * 16 + l15;
                #pragma unroll
                for (int kk = 0; kk < 2; ++kk)
                    af[ii][kk] = *(const bf16x8*)
                        &Ab[row * 64 + (((kk * 4 + quad) ^ lx)) * 8];
            }
            #pragma unroll
            for (int jj = 0; jj < NJ; ++jj) {
                int row = wn * (NT / 4) + nq * (NT / 8) + jj * 16 + l15;
                #pragma unroll
                for (int kk = 0; kk < 2; ++kk)
                    bfr[jj][kk] = *(const bf16x8*)
                        &Bb[row * 64 + (((kk * 4 + quad) ^ lx)) * 8];
            }

            #pragma unroll
            for (int ii = 0; ii < 4; ++ii)
                #pragma unroll
                for (int jj = 0; jj < NJ; ++jj)
                    #pragma unroll
                    for (int kk = 0; kk < 2; ++kk)
                        acc[mq * 4 + ii][nq * NJ + jj] =
                            __builtin_amdgcn_mfma_f32_16x16x32_bf16(
                                af[ii][kk], bfr[jj][kk],
                                acc[mq * 4 + ii][nq * NJ + jj], 0, 0, 0);
        }
        __syncthreads();
    }

    // epilogue: C/D layout col=lane&15, row=quad*4+r
    #pragma unroll
    for (int i = 0; i < 8; ++i) {
        int rowb = m0 + wm * 128 + i * 16 + quad * 4;
        float bvr[4];
        if (rowBias) {
            #pragma unroll
            for (int r = 0; r < 4; ++r) bvr[r] = bias[rowb + r];
        }
        #pragma unroll
        for (int jf = 0; jf < NT / 64; ++jf) {
            int col = n0 + wn * (NT / 4) + jf * 16 + l15;
            float bc = rowBias ? 0.f : bias[col];
            #pragma unroll
            for (int r = 0; r < 4; ++r) {
                float val = acc[i][jf][r] + (rowBias ? bvr[r] : bc);
                C[(size_t)(rowb + r) * D_MODEL + col] = (CT)val;
            }
        }
    }
    #undef STAGE_HALF
}

// ---------------------------------------------------------------------------
// Fused projection GEMM (R19-verified): 192 blocks x 512 thr, XCD-chunked.
// ---------------------------------------------------------------------------
__global__ __launch_bounds__(512, 2)
void k_gemm_proj(const bf16* __restrict__ cq, const bf16* __restrict__ ck,
                 const bf16* __restrict__ cv,
                 const bf16* __restrict__ cWq, const bf16* __restrict__ cWk,
                 const bf16* __restrict__ cWv,
                 const float* __restrict__ bq, const float* __restrict__ bk,
                 const float* __restrict__ bv,
                 bf16* __restrict__ qproj, bf16* __restrict__ kproj,
                 bf16* __restrict__ vt)
{
    extern __shared__ __align__(16) bf16 smem[];
    bf16* As0 = smem;            // 2 x 16384 elems
    bf16* Bs0 = smem + 32768;    // 2 x 16384 elems

    const int bid = blockIdx.x;
    const int tid = (bid & 7) * 24 + (bid >> 3);   // 0..191
    if (tid < 64) {
        gemm8_core<bf16, 256>(cq, cWq, bq, qproj,
                              (tid >> 2) * 256, (tid & 3) * 256, false, As0, Bs0);
    } else if (tid < 128) {
        int u = tid - 64;
        gemm8_core<bf16, 256>(ck, cWk, bk, kproj,
                              (u >> 2) * 256, (u & 3) * 256, false, As0, Bs0);
    } else {
        int v = tid - 128;
        int b = v >> 4, m = (v >> 2) & 3, n = v & 3;
        gemm8_core<bf16, 256>(cWv, cv + (size_t)b * W_N, bv,
                              vt + (size_t)b * W_N, m * 256, n * 256, true,
                              As0, Bs0);
    }
}

// O-projection: 128 blocks x 512 thr, 256x128 tiles (16 m x 8 n), XCD-chunked.
__global__ __launch_bounds__(512, 2)
void k_gemm_o(const bf16* __restrict__ A, const bf16* __restrict__ W,
              const float* __restrict__ bb, float* __restrict__ C)
{
    extern __shared__ __align__(16) bf16 smem[];
    bf16* As0 = smem;            // 2 x 16384 elems
    bf16* Bs0 = smem + 32768;    // 2 x 8192 elems

    const int bid = blockIdx.x;
    const int tid = (bid & 7) * 16 + (bid >> 3);   // 0..127
    gemm8_core<float, 128>(A, W, bb, C, (tid >> 3) * 256, (tid & 7) * 128,
                           false, As0, Bs0);
}

// ---------------------------------------------------------------------------
// Flash attention, QBLK=128, KVBLK=128 (R24), swapped QK^T + setprio.
// Grid (64, 8), 256 thr (4 waves); wave owns 32 q = 2 groups g of 16.
// Per 128-s tile: stage K/V(t+1) (8 GLD/wave: 16 frags each of K,V across
// 4 waves); for half h=0,1: QK^T (K frag (h*4+j)*2+kk) -> softmax -> b64
// P-store (T2 involution) -> wave_barrier -> pf read -> accl -> PV (V frag
// j*4+h*2+kk); ONE __syncthreads per tile (8 total vs 16). LDS dynamic:
// Ks 2x8192 + Vs 2x8192 + Past 8192 elems = 80KB -> 2 blocks/CU (same as
// grid-limited before; no occupancy loss).
// ---------------------------------------------------------------------------
__global__ __launch_bounds__(256)
void k_attn(const bf16* __restrict__ qproj, const bf16* __restrict__ kproj,
            const bf16* __restrict__ vt, const float* __restrict__ mbias_g,
            bf16* __restrict__ ctx)
{
    extern __shared__ __align__(16) bf16 asmem[];
    bf16* Ks   = asmem;           // 2 bufs x 8192 elems (128s x 64d)
    bf16* Vs   = asmem + 16384;   // 2 bufs x 8192 elems (64d x 128s)
    bf16* Past = asmem + 32768;   // 8192 elems, per-wave 2048, swizzled

    const int t    = threadIdx.x;
    const int lane = t & 63;
    const int w    = t >> 6;
    const int l15  = lane & 15;
    const int quad = lane >> 4;

    const int b  = blockIdx.x >> 4;
    const int h  = blockIdx.x & 15;
    const int q0 = blockIdx.y * 128;

    // stage K/V tile (128 s) into buffer kb: 16 frags each, 4 per wave.
    // K frag f: s-row block f>>1, d-32-block f&1. V frag f: d-16-block f>>2,
    // s-32-block f&3.
    #define STAGE_KV(s0s, kb) do {                                            \
        _Pragma("unroll")                                                     \
        for (int i = 0; i < 4; ++i) {                                         \
            int f = w * 4 + i;                                                \
            GLD(kproj + (size_t)(b * SEQ + (s0s) + (f >> 1) * 16 + l15)       \
                    * D_MODEL + h * HDIM + (f & 1) * 32 + quad * 8,           \
                Ks + (kb) * 8192 + f * 512);                                  \
            GLD(vt + (size_t)(b * 1024 + h * HDIM + (f >> 2) * 16 + l15)      \
                    * D_MODEL + (s0s) + (f & 3) * 32 + quad * 8,              \
                Vs + (kb) * 8192 + f * 512);                                  \
        }                                                                     \
    } while (0)

    STAGE_KV(0, 0);

    // Q fragments: direct per-lane 16B global loads (B-operand layout)
    bf16x8 qf[2][2];
    #pragma unroll
    for (int g = 0; g < 2; ++g)
        #pragma unroll
        for (int kk = 0; kk < 2; ++kk)
            qf[g][kk] = *(const bf16x8*)(qproj
                + (size_t)(b * SEQ + q0 + w * 32 + g * 16 + l15) * D_MODEL
                + h * HDIM + kk * 32 + quad * 8);

    __syncthreads();

    bf16x8 ones;
    #pragma unroll
    for (int e = 0; e < 8; ++e) ones[e] = (bf16)1.0f;

    floatx4 o[2][4] = {};
    floatx4 accl[2] = {};

    const int rswz = lane ^ ((lane >> 3) & 7);   // read-side swizzled chunk
    const float* __restrict__ mbb = mbias_g + b * SEQ;

    int cur = 0;
    for (int ti = 0; ti < 8; ++ti) {
        const int s0 = ti * 128;
        if (ti < 7)
            STAGE_KV(s0 + 128, cur ^ 1);

        const bf16* __restrict__ Kb = Ks + cur * 8192;
        const bf16* __restrict__ Vb = Vs + cur * 8192;

        #pragma unroll
        for (int hh = 0; hh < 2; ++hh) {
            // swapped QK^T: S^T[s][q] = mfma(A=K, B=Q), s-half hh
            floatx4 s_acc[2][4] = {};
            __builtin_amdgcn_s_setprio(1);
            #pragma unroll
            for (int j = 0; j < 4; ++j) {
                bf16x8 kf0 = *(const bf16x8*)
                    &Kb[((hh * 4 + j) * 2 + 0) * 512 + lane * 8];
                bf16x8 kf1 = *(const bf16x8*)
                    &Kb[((hh * 4 + j) * 2 + 1) * 512 + lane * 8];
                #pragma unroll
                for (int g = 0; g < 2; ++g) {
                    s_acc[g][j] = __builtin_amdgcn_mfma_f32_16x16x32_bf16(
                        kf0, qf[g][0], s_acc[g][j], 0, 0, 0);
                    s_acc[g][j] = __builtin_amdgcn_mfma_f32_16x16x32_bf16(
                        kf1, qf[g][1], s_acc[g][j], 0, 0, 0);
                }
            }
            __builtin_amdgcn_s_setprio(0);

            // softmax -> packed b64 P store (T2 involution, both sides)
            #pragma unroll
            for (int j = 0; j < 4; ++j) {
                float4 mb4 = *(const float4*)
                    &mbb[s0 + hh * 64 + j * 16 + quad * 4];
                int c = (j >> 1) * 64 + ((j & 1) * 2 + (quad >> 1)) * 16 + l15;
                int phys = c ^ ((c >> 3) & 7);
                #pragma unroll
                for (int g = 0; g < 2; ++g) {
                    bf16x4 pk;
                    pk[0] = (bf16)__builtin_amdgcn_exp2f(
                        fmaf(s_acc[g][j][0], SC2, mb4.x));
                    pk[1] = (bf16)__builtin_amdgcn_exp2f(
                        fmaf(s_acc[g][j][1], SC2, mb4.y));
                    pk[2] = (bf16)__builtin_amdgcn_exp2f(
                        fmaf(s_acc[g][j][2], SC2, mb4.z));
                    pk[3] = (bf16)__builtin_amdgcn_exp2f(
                        fmaf(s_acc[g][j][3], SC2, mb4.w));
                    *(bf16x4*)&Past[(w * 2 + g) * 1024 + phys * 8
                                    + (quad & 1) * 4] = pk;
                }
            }
            __builtin_amdgcn_wave_barrier();

            bf16x8 pf[2][2];
            #pragma unroll
            for (int g = 0; g < 2; ++g)
                #pragma unroll
                for (int kk = 0; kk < 2; ++kk)
                    pf[g][kk] = *(const bf16x8*)
                        &Past[(w * 2 + g) * 1024 + (kk * 64 + rswz) * 8];

            __builtin_amdgcn_s_setprio(1);
            #pragma unroll
            for (int g = 0; g < 2; ++g)
                #pragma unroll
                for (int kk = 0; kk < 2; ++kk)
                    accl[g] = __builtin_amdgcn_mfma_f32_16x16x32_bf16(
                        pf[g][kk], ones, accl[g], 0, 0, 0);

            #pragma unroll
            for (int j = 0; j < 4; ++j) {
                bf16x8 vf0 = *(const bf16x8*)
                    &Vb[(j * 4 + hh * 2 + 0) * 512 + lane * 8];
                bf16x8 vf1 = *(const bf16x8*)
                    &Vb[(j * 4 + hh * 2 + 1) * 512 + lane * 8];
                #pragma unroll
                for (int g = 0; g < 2; ++g) {
                    o[g][j] = __builtin_amdgcn_mfma_f32_16x16x32_bf16(
                        pf[g][0], vf0, o[g][j], 0, 0, 0);
                    o[g][j] = __builtin_amdgcn_mfma_f32_16x16x32_bf16(
                        pf[g][1], vf1, o[g][j], 0, 0, 0);
                }
            }
            __builtin_amdgcn_s_setprio(0);
        }

        __syncthreads();   // next K/V tile landed; buffers swap
        cur ^= 1;
    }

    #pragma unroll
    for (int g = 0; g < 2; ++g) {
        float inv[4];
        #pragma unroll
        for (int r = 0; r < 4; ++r)
            inv[r] = (accl[g][r] > 0.f) ? 1.f / accl[g][r] : 0.f;
        #pragma unroll
        for (int j = 0; j < 4; ++j)
            #pragma unroll
            for (int r = 0; r < 4; ++r) {
                int row = q0 + w * 32 + g * 16 + quad * 4 + r;
                int col = h * HDIM + j * 16 + l15;
                ctx[(size_t)(b * SEQ + row) * D_MODEL + col] =
                    (bf16)(o[g][j][r] * inv[r]);
            }
    }
    #undef STAGE_KV
}

// ---------------------------------------------------------------------------
extern "C" void kernel_launch(void* const* d_in, const int* in_sizes, int n_in,
                              void* d_out, int out_size, void* d_ws, size_t ws_size,
                              hipStream_t stream)
{
    // ws: [0,16K) mbias fp32 | [64K,+32MB) converted bf16 (q,k,v,Wq,Wk,Wv,Wo)
    //     | qproj 8MB | kproj 8MB | vt 8MB | ctx 8MB.   Total ~64.1MB.
    char* wsb = (char*)d_ws;
    float* mbias = (float*)wsb;
    bf16* cbase = (bf16*)(wsb + 65536);
    bf16 *cq = cbase, *ck = cq + ACT_N, *cv = ck + ACT_N;
    bf16 *cWq = cv + ACT_N, *cWk = cWq + W_N, *cWv = cWk + W_N, *cWo = cWv + W_N;
    bf16* qproj = cWo + W_N;
    bf16* kproj = qproj + ACT_N;
    bf16* vt    = kproj + ACT_N;
    bf16* ctx   = vt + ACT_N;
    float* out  = (float*)d_out;

    // allow big dynamic LDS (host-side, capture-safe)
    static bool attrset = false;
    if (!attrset) {
        hipFuncSetAttribute((const void*)k_gemm_proj,
                            hipFuncAttributeMaxDynamicSharedMemorySize, 131072);
        hipFuncSetAttribute((const void*)k_gemm_o,
                            hipFuncAttributeMaxDynamicSharedMemorySize, 131072);
        hipFuncSetAttribute((const void*)k_attn,
                            hipFuncAttributeMaxDynamicSharedMemorySize, 81920);
        attrset = true;
    }

    k_convert_all<<<8193, 256, 0, stream>>>(
        (const float*)d_in[0], (const float*)d_in[1], (const float*)d_in[2],
        (const float*)d_in[4], (const float*)d_in[6], (const float*)d_in[8],
        (const float*)d_in[10], cbase, (const unsigned*)d_in[3], mbias);

    k_gemm_proj<<<192, 512, 131072, stream>>>(cq, ck, cv, cWq, cWk, cWv,
                                              (const float*)d_in[5],
                                              (const float*)d_in[7],
                                              (const float*)d_in[9],
                                              qproj, kproj, vt);
    k_attn<<<dim3(64, 8), 256, 81920, stream>>>(qproj, kproj, vt, mbias, ctx);
    k_gemm_o<<<128, 512, 98304, stream>>>(ctx, cWo, (const float*)d_in[11], out);
}